// Round 3
// baseline (4109.752 us; speedup 1.0000x reference)
//
#include <hip/hip_runtime.h>
#include <hip/hip_bf16.h>
#include <stdint.h>

#define B_    64
#define T_    1024
#define DIN   136
#define DINP  160
#define H_    256
#define G4H   1024

typedef __bf16 bf16;
typedef __bf16 bf16x8 __attribute__((ext_vector_type(8)));
typedef float  floatx4 __attribute__((ext_vector_type(4)));
typedef int    int4v  __attribute__((ext_vector_type(4)));

// ---------------- pack kernels (validated R1/R2) ----------------
__global__ void k_pack_x(const float* __restrict__ x, bf16* __restrict__ xp) {
  const int n = T_ * B_ * DINP;
  for (int i = blockIdx.x * blockDim.x + threadIdx.x; i < n; i += gridDim.x * blockDim.x) {
    int k  = i % DINP;
    int tb = i / DINP;
    int b  = tb % B_;
    int t  = tb / B_;
    float v = 0.f;
    if (k < DIN) v = x[(b * T_ + t) * DIN + k];
    xp[i] = (bf16)v;   // layout [t][b][k], k zero-padded to 160
  }
}

// packed row r = 4*hid + gate  ->  orig row = gate*256 + hid
__global__ void k_pack_whh(const float* __restrict__ wf, const float* __restrict__ wb,
                           bf16* __restrict__ wp) {
  const int n = 2 * G4H * H_;
  for (int i = blockIdx.x * blockDim.x + threadIdx.x; i < n; i += gridDim.x * blockDim.x) {
    int k   = i & (H_ - 1);
    int r   = (i >> 8) & (G4H - 1);
    int dir = i >> 18;
    int orig = ((r & 3) << 8) | (r >> 2);
    const float* w = dir ? wb : wf;
    wp[i] = (bf16)w[orig * H_ + k];
  }
}

__global__ void k_pack_wih(const float* __restrict__ wf, const float* __restrict__ wb,
                           bf16* __restrict__ wp) {
  const int n = 2 * G4H * DINP;
  for (int i = blockIdx.x * blockDim.x + threadIdx.x; i < n; i += gridDim.x * blockDim.x) {
    int k   = i % DINP;
    int r   = (i / DINP) & (G4H - 1);
    int dir = i / (G4H * DINP);
    int orig = ((r & 3) << 8) | (r >> 2);
    const float* w = dir ? wb : wf;
    float v = (k < DIN) ? w[orig * DIN + k] : 0.f;
    wp[i] = (bf16)v;
  }
}

__global__ void k_pack_bias(const float* __restrict__ bihf, const float* __restrict__ bhhf,
                            const float* __restrict__ bihb, const float* __restrict__ bhhb,
                            float* __restrict__ bs) {
  int i = blockIdx.x * blockDim.x + threadIdx.x;
  if (i >= 2 * G4H) return;
  int r = i & (G4H - 1); int dir = i >> 10;
  int orig = ((r & 3) << 8) | (r >> 2);
  bs[i] = dir ? (bihb[orig] + bhhb[orig]) : (bihf[orig] + bhhf[orig]);
}

// ---------------- persistent LSTM: 128 autonomous waves, no LDS, no barriers ----------------
// wave = (dir 2) x (btile 4) x (qtr 4) x (w 4): owns 16 hid x 16 batch.
// Weights in registers (launch_bounds(256,1) -> 512 VGPR/wave budget).
// Exchange: sc1 stores to hbuf + per-wave monotonic flag; consumers bulk-load
// all 256 hid x 16 batch (8 x dwordx4, sc0 sc1) straight into MFMA B-fragments.
__global__ __launch_bounds__(256, 1) void k_lstm(
    const bf16* __restrict__ xp, const bf16* __restrict__ whhp,
    const bf16* __restrict__ wihp, const float* __restrict__ bs,
    bf16* __restrict__ hbuf, int* __restrict__ flags)
{
  const int tid = threadIdx.x;
  const int w   = tid >> 6;        // wave within wg 0..3
  const int l   = tid & 63;
  const int q   = l >> 4;
  const int m   = l & 15;

  const int wgid  = blockIdx.x;    // 0..31
  const int g     = wgid >> 2;     // dir*4 + btile
  const int qtr   = wgid & 3;
  const int dir   = g >> 2;
  const int btile = g & 3;
  const int rowbase = qtr * 256 + w * 64;   // packed gate-row base for this wave

  // ---- weight fragments into registers ----
  bf16x8 wf[4][8];      // Whh: 128 VGPRs
  bf16x8 wif[4][5];     // Wih:  80 VGPRs
  floatx4 bias[4];
#pragma unroll
  for (int tl = 0; tl < 4; ++tl) {
    const bf16* wr = whhp + (size_t)(dir * G4H + rowbase + tl * 16 + m) * H_ + q * 8;
#pragma unroll
    for (int c = 0; c < 8; ++c) wf[tl][c] = *(const bf16x8*)(wr + c * 32);
    const bf16* wr2 = wihp + (size_t)(dir * G4H + rowbase + tl * 16 + m) * DINP + q * 8;
#pragma unroll
    for (int c = 0; c < 5; ++c) wif[tl][c] = *(const bf16x8*)(wr2 + c * 32);
    bias[tl] = *(const floatx4*)(bs + dir * G4H + rowbase + tl * 16 + q * 4);
  }

  int* const flg      = flags + g * 16;
  const int  fidx     = qtr * 4 + w;
  unsigned* const hbuf_dw = (unsigned*)hbuf;
  const size_t hb_g = (size_t)g * T_;

  float cst[4] = {0.f, 0.f, 0.f, 0.f};

  bf16x8 xf[5];
  {
    const int xt0 = dir ? (T_ - 1) : 0;
    const bf16* xr = xp + (size_t)(xt0 * B_ + btile * 16 + m) * DINP + q * 8;
#pragma unroll
    for (int c = 0; c < 5; ++c) xf[c] = *(const bf16x8*)(xr + c * 32);
  }

  for (int t = 0; t < T_; ++t) {
    const int xt = dir ? (T_ - 1 - t) : t;
    floatx4 acc[4] = {bias[0], bias[1], bias[2], bias[3]};

    // input projection (independent of h) — fills the wait window
#pragma unroll
    for (int c = 0; c < 5; ++c) {
#pragma unroll
      for (int tl = 0; tl < 4; ++tl)
        acc[tl] = __builtin_amdgcn_mfma_f32_16x16x32_bf16(wif[tl][c], xf[c], acc[tl], 0, 0, 0);
    }
    // prefetch next step's x
    if (t + 1 < T_) {
      const int xtn = dir ? (T_ - 2 - t) : (t + 1);
      const bf16* xr = xp + (size_t)(xtn * B_ + btile * 16 + m) * DINP + q * 8;
#pragma unroll
      for (int c = 0; c < 5; ++c) xf[c] = *(const bf16x8*)(xr + c * 32);
    }

    if (t > 0) {
      // poll: all 16 waves of the group finished step t-1 (flag >= t; poison is negative)
      for (;;) {
        int v = t;
        if (l < 16) v = __hip_atomic_load(flg + l, __ATOMIC_RELAXED, __HIP_MEMORY_SCOPE_AGENT);
        if (__all(v >= t)) break;
      }
      __atomic_signal_fence(__ATOMIC_ACQUIRE);

      // bulk-load h(t-1): lane (q,m) gets B-frag dwords m*128 + c*16 + q*4 .. +3
      const int xtp = dir ? (xt + 1) : (xt - 1);
      const unsigned* p = hbuf_dw + (((hb_g + xtp) * 16 + m) << 7) + (q << 2);
      int4v h0, h1, h2, h3, h4, h5, h6, h7;
      asm volatile(
        "global_load_dwordx4 %0, %[a], off sc0 sc1\n\t"
        "global_load_dwordx4 %1, %[a], off offset:64 sc0 sc1\n\t"
        "global_load_dwordx4 %2, %[a], off offset:128 sc0 sc1\n\t"
        "global_load_dwordx4 %3, %[a], off offset:192 sc0 sc1\n\t"
        "global_load_dwordx4 %4, %[a], off offset:256 sc0 sc1\n\t"
        "global_load_dwordx4 %5, %[a], off offset:320 sc0 sc1\n\t"
        "global_load_dwordx4 %6, %[a], off offset:384 sc0 sc1\n\t"
        "global_load_dwordx4 %7, %[a], off offset:448 sc0 sc1\n\t"
        "s_waitcnt vmcnt(0)"
        : "=v"(h0), "=v"(h1), "=v"(h2), "=v"(h3),
          "=v"(h4), "=v"(h5), "=v"(h6), "=v"(h7)
        : [a] "v"(p)
        : "memory");

#pragma unroll
      for (int tl = 0; tl < 4; ++tl) {
        acc[tl] = __builtin_amdgcn_mfma_f32_16x16x32_bf16(wf[tl][0], __builtin_bit_cast(bf16x8, h0), acc[tl], 0, 0, 0);
        acc[tl] = __builtin_amdgcn_mfma_f32_16x16x32_bf16(wf[tl][1], __builtin_bit_cast(bf16x8, h1), acc[tl], 0, 0, 0);
        acc[tl] = __builtin_amdgcn_mfma_f32_16x16x32_bf16(wf[tl][2], __builtin_bit_cast(bf16x8, h2), acc[tl], 0, 0, 0);
        acc[tl] = __builtin_amdgcn_mfma_f32_16x16x32_bf16(wf[tl][3], __builtin_bit_cast(bf16x8, h3), acc[tl], 0, 0, 0);
        acc[tl] = __builtin_amdgcn_mfma_f32_16x16x32_bf16(wf[tl][4], __builtin_bit_cast(bf16x8, h4), acc[tl], 0, 0, 0);
        acc[tl] = __builtin_amdgcn_mfma_f32_16x16x32_bf16(wf[tl][5], __builtin_bit_cast(bf16x8, h5), acc[tl], 0, 0, 0);
        acc[tl] = __builtin_amdgcn_mfma_f32_16x16x32_bf16(wf[tl][6], __builtin_bit_cast(bf16x8, h6), acc[tl], 0, 0, 0);
        acc[tl] = __builtin_amdgcn_mfma_f32_16x16x32_bf16(wf[tl][7], __builtin_bit_cast(bf16x8, h7), acc[tl], 0, 0, 0);
      }
    }

    // in-lane cell update: reg0=i reg1=f reg2=g reg3=o for (hid = rowbase/4 + tl*4 + q, batch = btile*16+m)
    unsigned short hu[4];
#pragma unroll
    for (int tl = 0; tl < 4; ++tl) {
      float pi = acc[tl][0], pf = acc[tl][1], pg = acc[tl][2], po = acc[tl][3];
      float ig = 1.f / (1.f + __expf(-pi));
      float fg = 1.f / (1.f + __expf(-pf));
      float og = 1.f / (1.f + __expf(-po));
      float gcl = fminf(fmaxf(pg, -15.f), 15.f);
      float e2  = __expf(2.f * gcl);
      float gg  = (e2 - 1.f) / (e2 + 1.f);
      float c   = fg * cst[tl] + ig * gg;
      cst[tl]   = c;
      float ccl = fminf(fmaxf(c, -15.f), 15.f);
      float ec  = __expf(2.f * ccl);
      float hv  = og * ((ec - 1.f) / (ec + 1.f));
      bf16 hb = (bf16)hv;
      hu[tl] = __builtin_bit_cast(unsigned short, hb);
    }

    // publish own 16 hid x 16 batch (512B): pair lanes q<->q^1, even-q stores dwords
    {
      const size_t obase = ((hb_g + xt) * 16 + m) * 128 + (size_t)(qtr * 32 + w * 8);
#pragma unroll
      for (int tl = 0; tl < 4; ++tl) {
        int ov = __shfl_xor((int)(unsigned)hu[tl], 16);
        if ((q & 1) == 0) {
          unsigned dw = (unsigned)hu[tl] | ((unsigned)ov << 16);
          __hip_atomic_store(hbuf_dw + obase + tl * 2 + (q >> 1), dw,
                             __ATOMIC_RELAXED, __HIP_MEMORY_SCOPE_AGENT);
        }
      }
    }

    // drain publish stores to the coherence point, then raise this wave's flag
    asm volatile("s_waitcnt vmcnt(0)" ::: "memory");
    __atomic_signal_fence(__ATOMIC_RELEASE);
    if (l == 0)
      __hip_atomic_store(flg + fidx, t + 1, __ATOMIC_RELAXED, __HIP_MEMORY_SCOPE_AGENT);
  }
}

// ---------------- FC epilogue ----------------
// one block per t; hbuf layout [g=dir*4+btile][xt][m][hid 256] bf16
__global__ __launch_bounds__(512) void k_fc(const bf16* __restrict__ hbuf,
                                            const float* __restrict__ fcw,
                                            const float* __restrict__ fcb,
                                            float* __restrict__ out)
{
  __shared__ float wsm[5 * 512];
  __shared__ unsigned short hl[64 * 258];      // [b][hid 256 pad 258]
  const int tid = threadIdx.x;
  const int t   = blockIdx.x;
  for (int i = tid; i < 2560; i += 512) wsm[i] = fcw[i];
  const int o = tid / 64, b = tid & 63;
  float acc = 0.f;
  for (int dirc = 0; dirc < 2; ++dirc) {
    __syncthreads();
    for (int i = tid; i < 8192; i += 512) {
      int bb = i >> 7, dd = i & 127;
      int gg = dirc * 4 + (bb >> 4), mm = bb & 15;
      ((unsigned*)hl)[bb * 129 + dd] =
          ((const unsigned*)hbuf)[((size_t)(gg * T_ + t) * 16 + mm) * 128 + dd];
    }
    __syncthreads();
    if (tid < 320) {
      const float* wr = &wsm[o * 512 + dirc * 256];
      const unsigned short* hr = &hl[b * 258];
      float a = 0.f;
#pragma unroll 8
      for (int h = 0; h < 256; ++h) {
        unsigned u = ((unsigned)hr[h]) << 16;
        a += wr[h] * __builtin_bit_cast(float, u);
      }
      acc += a;
    }
  }
  if (tid < 320) out[((size_t)b * T_ + t) * 5 + o] = acc + fcb[o];
}

// ---------------- launcher ----------------
extern "C" void kernel_launch(void* const* d_in, const int* in_sizes, int n_in,
                              void* d_out, int out_size, void* d_ws, size_t ws_size,
                              hipStream_t stream) {
  const float* x    = (const float*)d_in[0];
  const float* wihf = (const float*)d_in[1];
  const float* whhf = (const float*)d_in[2];
  const float* bihf = (const float*)d_in[3];
  const float* bhhf = (const float*)d_in[4];
  const float* wihb = (const float*)d_in[5];
  const float* whhb = (const float*)d_in[6];
  const float* bihb = (const float*)d_in[7];
  const float* bhhb = (const float*)d_in[8];
  const float* fcw  = (const float*)d_in[9];
  const float* fcb  = (const float*)d_in[10];
  float* out = (float*)d_out;

  char* ws = (char*)d_ws;
  bf16*  xp    = (bf16*)(ws + 0);            // 20,971,520 B
  bf16*  whhp  = (bf16*)(ws + 20971520);     //  1,048,576 B
  bf16*  wihp  = (bf16*)(ws + 22020096);     //    655,360 B
  float* bsum  = (float*)(ws + 22675456);    //      8,192 B
  int*   flags = (int*)(ws + 22683648);      //        512 B (poison 0xAA.. is negative -> no memset)
  bf16*  hseq  = (bf16*)(ws + 22716416);     // 67,108,864 B  [g][xt][m][hid]
  (void)in_sizes; (void)n_in; (void)out_size; (void)ws_size;

  k_pack_x   <<<4096, 256, 0, stream>>>(x, xp);
  k_pack_whh <<<1024, 256, 0, stream>>>(whhf, whhb, whhp);
  k_pack_wih <<<640,  256, 0, stream>>>(wihf, wihb, wihp);
  k_pack_bias<<<8,    256, 0, stream>>>(bihf, bhhf, bihb, bhhb, bsum);
  k_lstm     <<<32,   256, 0, stream>>>(xp, whhp, wihp, bsum, hseq, flags);
  k_fc       <<<1024, 512, 0, stream>>>(hseq, fcw, fcb, out);
}